// Round 8
// baseline (493.461 us; speedup 1.0000x reference)
//
#include <hip/hip_runtime.h>
#include <math.h>

#define D_    64
#define K_    1024
#define N_    131072
#define HW_   4096
#define ROWS  128
#define KC    128
#define NT    256
#define NCHUNK 8           // 8 chunks x 128 codes
#define NPASS  16          // 16 d-passes per chunk, 4 d each

typedef unsigned long long ull;

__device__ __forceinline__ float f4c(const float4& v, int c) {
    return c == 0 ? v.x : c == 1 ? v.y : c == 2 ? v.z : v.w;  // c is compile-time
}

__global__ __launch_bounds__(256)
void vq_init(const float* __restrict__ emb, int* __restrict__ hist,
             double* __restrict__ ssqd, float* __restrict__ e2g) {
    int k = blockIdx.x * 256 + threadIdx.x;
    if (k < K_) {
        hist[k] = 0;
        float s = 0.0f;
        const float* e = emb + (size_t)k * D_;
        #pragma unroll
        for (int d = 0; d < D_; ++d) s = fmaf(e[d], e[d], s);  // ascending d
        e2g[k] = s;
    }
    if (k == 0 && blockIdx.x == 0) *ssqd = 0.0;
}

// One pass: prefetch next e-fragment into ef[BUF^1], compute 4 d's from ef[BUF].
#define PASS(BUF, PP)                                                          \
    {                                                                          \
        const int gn = c * NPASS + (PP) + 1;                                   \
        if (gn < NCHUNK * NPASS) {                                             \
            const int cn = gn >> 4, pn = gn & 15;                              \
            const float* eb = emb + (size_t)(cn * KC + kk0) * D_ + pn * 4;     \
            _Pragma("unroll")                                                  \
            for (int j = 0; j < 8; ++j)                                        \
                ef[(BUF) ^ 1][j] = *(const float4*)(eb + (size_t)j * D_);      \
        }                                                                      \
        const float* ztp = zt + (PP) * 4 * ROWS + r0;                          \
        _Pragma("unroll")                                                      \
        for (int dd = 0; dd < 4; ++dd) {                                       \
            const float4 za0 = *(const float4*)(ztp + dd * ROWS);              \
            const float4 za1 = *(const float4*)(ztp + dd * ROWS + 4);          \
            const float zr[8] = {za0.x, za0.y, za0.z, za0.w,                   \
                                 za1.x, za1.y, za1.z, za1.w};                  \
            _Pragma("unroll")                                                  \
            for (int i = 0; i < 8; ++i)                                        \
                _Pragma("unroll")                                              \
                for (int j = 0; j < 8; ++j)                                    \
                    acc[i][j] = fmaf(zr[i], f4c(ef[(BUF)][j], dd), acc[i][j]); \
        }                                                                      \
    }

__global__ __launch_bounds__(NT)
void vq_main(const float* __restrict__ x, const float* __restrict__ emb,
             const float* __restrict__ e2g, float* __restrict__ zq_out,
             int* __restrict__ hist, double* __restrict__ ssqd) {
    __shared__ __align__(16) float zt[D_ * ROWS];   // 32 KB [d][r]
    __shared__ __align__(16) float r2s[ROWS];
    __shared__ __align__(16) int   bidxs[ROWS];
    __shared__ float wsum[NT / 64];

    const int tid = threadIdx.x;
    const int bid = blockIdx.x;
    const int n0  = bid * ROWS;
    const int b   = n0 >> 12;
    const int hw0 = n0 & (HW_ - 1);
    const float* xb = x + (size_t)b * (D_ * HW_) + hw0;

    // ---- stage z tile (coalesced float4) ----
    #pragma unroll
    for (int i = 0; i < 8; ++i) {
        int li = i * NT + tid;          // 0..2047
        int d  = li >> 5;
        int r4 = (li & 31) << 2;
        *(float4*)(zt + d * ROWS + r4) = *(const float4*)(xb + (size_t)d * HW_ + r4);
    }
    __syncthreads();

    // ---- r2 per row (ascending-d fma chain: bitwise == rounds 1-7) ----
    if (tid < ROWS) {
        float s = 0.0f;
        for (int d = 0; d < D_; ++d) { float z = zt[d * ROWS + tid]; s = fmaf(z, z, s); }
        r2s[tid] = s;
    }
    __syncthreads();
    // ---- main loop is barrier-free from here ----

    const int kg  = tid & 15;           // 16 k-groups x 8 codes
    const int rg  = tid >> 4;           // 16 r-groups x 8 rows
    const int r0  = rg * 8;
    const int kk0 = kg * 8;

    float r2v[8];
    *(float4*)(r2v)     = *(const float4*)(r2s + r0);
    *(float4*)(r2v + 4) = *(const float4*)(r2s + r0 + 4);

    float bd[8]; int bk[8];
    #pragma unroll
    for (int i = 0; i < 8; ++i) { bd[i] = 3.4e38f; bk[i] = 0; }

    float4 ef[2][8];
    {   // prologue: pass g=0 (c=0, pn=0) into ef[0]
        const float* eb = emb + (size_t)kk0 * D_;
        #pragma unroll
        for (int j = 0; j < 8; ++j)
            ef[0][j] = *(const float4*)(eb + (size_t)j * D_);
    }

    for (int c = 0; c < NCHUNK; ++c) {
        float acc[8][8];
        #pragma unroll
        for (int i = 0; i < 8; ++i)
            #pragma unroll
            for (int j = 0; j < 8; ++j) acc[i][j] = 0.0f;

        #pragma unroll 1
        for (int ph = 0; ph < NPASS / 2; ++ph) {
            PASS(0, 2 * ph)
            PASS(1, 2 * ph + 1)
        }

        // ---- dist + running argmin (strict <, ascending k) ----
        const int kbase = c * KC;
        float e2v[8];
        *(float4*)(e2v)     = *(const float4*)(e2g + kbase + kk0);
        *(float4*)(e2v + 4) = *(const float4*)(e2g + kbase + kk0 + 4);
        #pragma unroll
        for (int i = 0; i < 8; ++i) {
            #pragma unroll
            for (int j = 0; j < 8; ++j) {
                float dist = fmaf(-2.0f, acc[i][j], r2v[i] + e2v[j]);  // bitwise == rounds 1-7
                int k = kbase + kk0 + j;
                if (dist < bd[i]) { bd[i] = dist; bk[i] = k; }
            }
        }
    }

    // ---- cross-kg argmin: 16-lane butterfly on packed (distbits<<32 | k) ----
    #pragma unroll
    for (int i = 0; i < 8; ++i) {
        ull p = ((ull)__float_as_uint(bd[i]) << 32) | (unsigned int)bk[i];
        #pragma unroll
        for (int off = 1; off < 16; off <<= 1) {
            ull q = __shfl_xor(p, off, 64);
            if (q < p) p = q;
        }
        if (kg == 0) {
            int k = (int)(p & 0xffffffffull);
            bidxs[r0 + i] = k;
            atomicAdd(&hist[k], 1);
        }
    }
    __syncthreads();

    // ---- epilogue: z from LDS, gather e (L2-hot), scalar coalesced stores ----
    float ls = 0.0f;
    float* outb = zq_out + (size_t)b * (D_ * HW_) + hw0;
    #pragma unroll 4
    for (int it = 0; it < 32; ++it) {
        int li = it * NT + tid;         // 0..8191
        int r  = li & (ROWS - 1);
        int d  = li >> 7;
        int k  = bidxs[r];
        float e = emb[(size_t)k * D_ + d];
        float z = zt[d * ROWS + r];
        float t = e - z;
        ls = fmaf(t, t, ls);
        outb[(size_t)d * HW_ + r] = z + t;
    }

    #pragma unroll
    for (int o = 32; o > 0; o >>= 1) ls += __shfl_down(ls, o, 64);
    if ((tid & 63) == 0) wsum[tid >> 6] = ls;
    __syncthreads();
    if (tid == 0) {
        float s = 0.0f;
        #pragma unroll
        for (int w = 0; w < NT / 64; ++w) s += wsum[w];
        atomicAdd(ssqd, (double)s);
    }
}

__global__ __launch_bounds__(1024)
void vq_final(const int* __restrict__ hist, const double* __restrict__ ssqd,
              float* __restrict__ out_loss, float* __restrict__ out_perp) {
    __shared__ float wred[16];
    int t = threadIdx.x;
    float cnt = (float)hist[t];
    float em  = cnt / (float)N_;
    float s   = em * logf(em + 1e-10f);
    #pragma unroll
    for (int o = 32; o > 0; o >>= 1) s += __shfl_down(s, o, 64);
    if ((t & 63) == 0) wred[t >> 6] = s;
    __syncthreads();
    if (t == 0) {
        float tot = 0.0f;
        for (int w = 0; w < 16; ++w) tot += wred[w];
        *out_perp = expf(-tot);
        float mse = (float)(*ssqd / (double)((size_t)N_ * D_));
        *out_loss = mse + 0.25f * mse;
    }
}

extern "C" void kernel_launch(void* const* d_in, const int* in_sizes, int n_in,
                              void* d_out, int out_size, void* d_ws, size_t ws_size,
                              hipStream_t stream) {
    const float* x   = (const float*)d_in[0];
    const float* emb = (const float*)d_in[1];
    float* out  = (float*)d_out;
    float* loss = out;
    float* zq   = out + 1;
    float* perp = out + 1 + (size_t)N_ * D_;
    int*    hist = (int*)d_ws;
    double* ssqd = (double*)((char*)d_ws + K_ * sizeof(int));
    float*  e2g  = (float*)((char*)d_ws + K_ * sizeof(int) + 16);

    vq_init<<<dim3(4), dim3(256), 0, stream>>>(emb, hist, ssqd, e2g);
    vq_main<<<dim3(N_ / ROWS), dim3(NT), 0, stream>>>(x, emb, e2g, zq, hist, ssqd);
    vq_final<<<dim3(1), dim3(1024), 0, stream>>>(hist, ssqd, loss, perp);
}